// Round 15
// baseline (139.232 us; speedup 1.0000x reference)
//
#include <hip/hip_runtime.h>
#include <hip/hip_fp16.h>
#include <math.h>

#define N 8192
#define H 64
#define B 8
#define MAXDEG 128
#define REPS 16
#define TILE 256                 // src rows per LDS tile (64 KB)
#define NPH  (N / TILE)          // 32 phases

// ---- workspace layout (bytes) ----
// zeroed each call by k_zero:
#define OFF_CNT  0ULL            // 8192 u32 = 32768
#define OFF_WR   32768ULL        // REPS*512 f32 = 32768
#define OFF_PR   65536ULL        // 32768
#define OFF_NLR  98304ULL        // REPS*8 f32 = 512
#define ZERO_END 98816ULL        // /16 = 6176 float4
// not zeroed:
#define OFF_COLS 98816ULL        // 8192*128 u16 = 2,097,152
#define OFF_TGT  2195968ULL      // 512 f32
#define OFF_UV   2198016ULL      // 3*64 f32
#define OFF_REC  2198784ULL      // 8193*64 u32 = 2,097,408 (256B rows)

// K0: zero cnt + replica accumulators (~97 KB)
__global__ __launch_bounds__(256) void k_zero(float4* __restrict__ p) {
    unsigned i = blockIdx.x * 256u + threadIdx.x;
    if (i < (unsigned)(ZERO_END / 16))
        p[i] = make_float4(0.f, 0.f, 0.f, 0.f);
}

// K1: append edges (1 edge/thread; dedup in K2)
__global__ __launch_bounds__(256) void k_edges(const int* __restrict__ ei, int nE,
                                               unsigned* __restrict__ cnt,
                                               unsigned short* __restrict__ cols) {
    int e = blockIdx.x * 256 + threadIdx.x;
    if (e >= nE) return;
    int r = ei[e];
    int c = ei[nE + e];
    unsigned k = atomicAdd(&cnt[r], 1u);
    if (k < MAXDEG) cols[r * MAXDEG + k] = (unsigned short)c;
}

// 64-lane bitonic sort (ascending), one key per lane
__device__ __forceinline__ int bitonic64(int v, int lane) {
#pragma unroll
    for (int k = 2; k <= 64; k <<= 1) {
#pragma unroll
        for (int j = k >> 1; j >= 1; j >>= 1) {
            int other = __shfl_xor(v, j, 64);
            bool lower = (lane & j) == 0;            // lane < partner
            bool up = (lane & k) == 0;               // ascending region
            bool keepMin = (lower == up);
            int mn = min(v, other), mx = max(v, other);
            v = keepMin ? mn : mx;
        }
    }
    return v;
}

// K2: per-wave {dedup -> SORTED padded col list -> dis -> packed record}.
// rec[m][lane] u32 = f16(dis_m*(W_g@ne[m])_lane) << 16 | f16(aux_lane)
// aux: lane<8: dis*x0_b; 8..15: dis*x1_b; 16: dis; 17..24: pmask_b; else 0.
// cols[r][0..63] ascending, dups/padding = N (sentinel, sorts last).
__global__ __launch_bounds__(256) void k_prep(const float* __restrict__ ne,
                                              const float* __restrict__ W_g,
                                              const float* __restrict__ W_sp,
                                              const float* __restrict__ b_sp,
                                              const float* __restrict__ x,
                                              const float* __restrict__ pmask,
                                              unsigned* __restrict__ cnt,
                                              unsigned short* __restrict__ cols,
                                              unsigned* __restrict__ rec,
                                              float* __restrict__ uvec) {
    __shared__ float wgs[H * 65];                // padded W_g
    __shared__ unsigned short ls[4][MAXDEG];     // dedup staging
    const int tid = threadIdx.x, lane = tid & 63, wv = tid >> 6;
    const int bid = blockIdx.x;

    for (int e = tid; e < H * H; e += 256)
        wgs[(e >> 6) * 65 + (e & 63)] = W_g[e];
    __syncthreads();

    float wr[H];
#pragma unroll
    for (int k = 0; k < H; ++k) wr[k] = wgs[lane * 65 + k];

    if (bid == 0 && wv == 0) {   // uvec = {W_g@Wsp0, W_g@Wsp1, W_g@b_sp}
        float v0 = W_sp[lane * 2 + 0], v1 = W_sp[lane * 2 + 1], vb = b_sp[lane];
        float a0 = 0.f, a1 = 0.f, a2 = 0.f;
#pragma unroll
        for (int k = 0; k < H; ++k) {
            a0 = fmaf(wr[k], __shfl(v0, k, 64), a0);
            a1 = fmaf(wr[k], __shfl(v1, k, 64), a1);
            a2 = fmaf(wr[k], __shfl(vb, k, 64), a2);
        }
        uvec[lane] = a0; uvec[64 + lane] = a1; uvec[128 + lane] = a2;
    }

    for (int i = 0; i < 2; ++i) {
        const int r = (bid * 4 + wv) * 2 + i;
        const int kraw = min((int)cnt[r], MAXDEG);
        unsigned short* cl = &cols[r * MAXDEG];
        for (int t = lane; t < kraw; t += 64) ls[wv][t] = cl[t];
        int c0 = (lane < kraw) ? (int)ls[wv][lane] : -1;
        int dup0 = 0;
        for (int j = 0; j < lane && j < kraw; ++j)
            dup0 |= ((int)ls[wv][j] == c0);
        unsigned long long m0 = __ballot((lane < kraw) && !dup0);
        unsigned long long below = (1ULL << lane) - 1ULL;
        unsigned tot = __popcll(m0);
        if (kraw <= 64) {
            // register path: distinct -> value, dup/pad -> sentinel N; sort; store
            int sv = ((lane < kraw) && !dup0) ? c0 : N;
            sv = bitonic64(sv, lane);
            cl[lane] = (unsigned short)sv;
        } else {                                  // wave-uniform, rare
            if ((lane < kraw) && !dup0)
                cl[__popcll(m0 & below)] = (unsigned short)c0;
            const int i1 = lane + 64;
            int c1 = (i1 < kraw) ? (int)ls[wv][i1] : -2;
            int dup1 = 0;
            for (int j = 0; j < i1 && j < kraw; ++j)
                dup1 |= ((int)ls[wv][j] == c1);
            unsigned long long m1 = __ballot((i1 < kraw) && !dup1);
            if ((i1 < kraw) && !dup1)
                cl[tot + __popcll(m1 & below)] = (unsigned short)c1;
            tot += __popcll(m1);
            // read back first 64 distinct, sort, store (tail [64,tot) stays unsorted)
            int sv = (lane < (int)min(tot, 64u)) ? (int)cl[lane] : N;
            sv = bitonic64(sv, lane);
            cl[lane] = (unsigned short)sv;
        }
        if (lane == 0) cnt[r] = tot;
        const float dis = rsqrtf((float)(tot + 1u));

        // --- aux for row r ---
        float xvx = 0.f, xvy = 0.f, pm = 0.f;
        if (lane < 8) {
            float2 t2 = ((const float2*)x)[lane * N + r];
            xvx = t2.x; xvy = t2.y;
        }
        if (lane >= 17 && lane < 25) pm = pmask[(lane - 17) * N + r];
        float yv = __shfl(xvy, lane & 7, 64);
        float aux = (lane < 8)   ? dis * xvx
                  : (lane < 16)  ? dis * yv
                  : (lane == 16) ? dis
                  : (lane < 25)  ? pm : 0.f;

        // --- P part: dis * (W_g @ ne[r])_lane ---
        const float4* ne4 = (const float4*)(ne + (size_t)r * H);
        float acc = 0.f;
#pragma unroll
        for (int kk = 0; kk < 16; ++kk) {
            float4 h4 = ne4[kk];
            acc = fmaf(wr[4 * kk + 0], h4.x, acc);
            acc = fmaf(wr[4 * kk + 1], h4.y, acc);
            acc = fmaf(wr[4 * kk + 2], h4.z, acc);
            acc = fmaf(wr[4 * kk + 3], h4.w, acc);
        }
        unsigned w = ((unsigned)__half_as_ushort(__float2half(dis * acc)) << 16)
                   |  (unsigned)__half_as_ushort(__float2half(aux));
        rec[(size_t)r * 64 + lane] = w;
    }
}

// K3: source-tiled SpMM through LDS — NO random global gathers.
// 256 blocks x 1024 thr (16 waves); block owns 32 dest rows (2/wave).
// 32 phases: stream 256-src-row tile (64 KB) into LDS coalesced, then each
// wave pointer-walks its SORTED col lists, consuming in-tile neighbors via
// conflict-free ds_read_b32. Epilogue overlays reduction arrays on the tile.
__global__ __launch_bounds__(1024) void k_spmm(const unsigned* __restrict__ rec,
                                               const unsigned* __restrict__ cnt,
                                               const unsigned short* __restrict__ cols,
                                               const float* __restrict__ uvec,
                                               const float* __restrict__ b_g,
                                               const int* __restrict__ target,
                                               float* __restrict__ wr_,
                                               float* __restrict__ pr_,
                                               float* __restrict__ nlr,
                                               float* __restrict__ tgt) {
    __shared__ unsigned tile[TILE * 64];          // 64 KB (reused as lw/lp/lnl)
    const int tid = threadIdx.x;
    const int lane = tid & 63, wv = tid >> 6;
    const int r0 = blockIdx.x * 32 + wv * 2;
    const int r1 = r0 + 1;

    const float u0 = uvec[lane], u1 = uvec[64 + lane], ub = uvec[128 + lane];
    const float bg = b_g[lane];
    int tg[B];
#pragma unroll
    for (int b = 0; b < B; ++b) tg[b] = target[b];

    // own-row records (eye terms) + sorted col regs
    unsigned v0_ = rec[(size_t)r0 * 64 + lane];
    unsigned v1_ = rec[(size_t)r1 * 64 + lane];
    float2 f0 = __half22float2(*(const __half2*)&v0_);   // .y=P .x=aux
    float2 f1 = __half22float2(*(const __half2*)&v1_);
    float sp0 = f0.y, sx0 = f0.x, sp1 = f1.y, sx1 = f1.x;
    const int kc0 = min((int)cnt[r0], MAXDEG);
    const int kc1 = min((int)cnt[r1], MAXDEG);
    const int creg0 = (int)cols[r0 * MAXDEG + lane];     // sorted, padded w/ N
    const int creg1 = (int)cols[r1 * MAXDEG + lane];
    int kp0 = 0, kp1 = 0;

    for (int t = 0; t < NPH; ++t) {
        const int base = t * TILE, tend = base + TILE;
        __syncthreads();                          // prev walk done
        {
            const uint4* src = (const uint4*)(rec + (size_t)base * 64);
            uint4* dst = (uint4*)tile;
#pragma unroll
            for (int j = 0; j < 4; ++j)
                dst[tid + j * 1024] = src[tid + j * 1024];
        }
        __syncthreads();                          // tile ready
        while (kp0 < 64) {
            int c = __shfl(creg0, kp0, 64);       // wave-uniform index
            if (c >= tend) break;                 // sorted; sentinel N breaks too
            unsigned v = tile[(c - base) * 64 + lane];
            float2 f = __half22float2(*(const __half2*)&v);
            sp0 += f.y; sx0 += f.x; ++kp0;
        }
        while (kp1 < 64) {
            int c = __shfl(creg1, kp1, 64);
            if (c >= tend) break;
            unsigned v = tile[(c - base) * 64 + lane];
            float2 f = __half22float2(*(const __half2*)&v);
            sp1 += f.y; sx1 += f.x; ++kp1;
        }
    }
    // rare tail: degree > 64 (unsorted region [64, kc))
    for (int kk = 64; kk < kc0; ++kk) {
        unsigned v = rec[(size_t)((int)cols[r0 * MAXDEG + kk]) * 64 + lane];
        float2 f = __half22float2(*(const __half2*)&v);
        sp0 += f.y; sx0 += f.x;
    }
    for (int kk = 64; kk < kc1; ++kk) {
        unsigned v = rec[(size_t)((int)cols[r1 * MAXDEG + kk]) * 64 + lane];
        float2 f = __half22float2(*(const __half2*)&v);
        sp1 += f.y; sx1 += f.x;
    }

    // ---- epilogue: overlay reduction arrays on tile LDS ----
    __syncthreads();                              // everyone done with tile
    float* lw  = (float*)tile;                    // 512
    float* lp  = lw + 512;                        // 512
    float* lnl = lp + 512;                        // 8
    if (tid < 1032) ((float*)tile)[tid] = 0.f;
    __syncthreads();

#pragma unroll
    for (int i = 0; i < 2; ++i) {
        const float sp = i ? sp1 : sp0;
        const float sx = i ? sx1 : sx0;
        const float fx = i ? f1.x : f0.x;
        const int   r  = i ? r1 : r0;
        const float dis_r = __shfl(fx, 16, 64);
        const float rdis = 1.0f / dis_r;
        const float sd = __shfl(sx, 16, 64);
        const float base2 = fmaf(sd, ub, sp);
#pragma unroll
        for (int b = 0; b < B; ++b) {
            float sa = __shfl(sx, b, 64);
            float sb = __shfl(sx, 8 + b, 64);
            float sc = __shfl(fx, 8 + b, 64) * rdis;    // score = x1[b][r]
            float mk = __shfl(fx, 17 + b, 64);          // pmask[b][r]
            float v = fmaf(sa, u0, fmaf(sb, u1, base2));
            float z = fmaxf(fmaf(dis_r, v, bg), 0.f);
            atomicAdd(&lw[b * H + lane], z * sc);
            atomicAdd(&lp[b * H + lane], (z + __logf(1.f + __expf(-z))) * mk);
            if (r == tg[b]) tgt[b * H + lane] = z;
        }
        if (lane < 8) atomicAdd(&lnl[lane], fx * rdis); // x0[b][r]
    }
    __syncthreads();

    // block -> global: one atomic per element
    const int rep = blockIdx.x & (REPS - 1);
    if (tid < 512)           atomicAdd(&wr_[rep * 512 + tid], lw[tid]);
    else if (tid < 1024)     atomicAdd(&pr_[rep * 512 + tid - 512], lp[tid - 512]);
    if (tid >= 1024 - B && tid < 1024) {
        int b = tid - (1024 - B);
        atomicAdd(&nlr[rep * B + b], lnl[b]);
    }
}

// K4: reduce replicas, per-batch dots, sigmoid
__global__ __launch_bounds__(512) void k_final(const float* __restrict__ wr_,
                                               const float* __restrict__ pr_,
                                               const float* __restrict__ nlr,
                                               const float* __restrict__ tgt,
                                               const float* __restrict__ W_d,
                                               const float* __restrict__ b_d,
                                               const float* __restrict__ W_a,
                                               const float* __restrict__ b_a,
                                               const float* __restrict__ prereq_w,
                                               float* __restrict__ out) {
    int tid = threadIdx.x, b = tid >> 6, h = tid & 63;
    float ws = 0.f, ps = 0.f, nlv = 0.f;
#pragma unroll
    for (int rep = 0; rep < REPS; ++rep) {
        ws  += wr_[rep * 512 + b * H + h];
        ps  += pr_[rep * 512 + b * H + h];
        nlv += nlr[rep * B + b];
    }
    float nl = fmaxf(nlv, 1.0f);
    float ap = (ws / nl) * W_a[h];
    float dp = tgt[b * H + h] * W_d[h];
    float pp = ps;
    for (int off = 32; off; off >>= 1) {
        ap += __shfl_down(ap, off, 64);
        dp += __shfl_down(dp, off, 64);
        pp += __shfl_down(pp, off, 64);
    }
    if (h == 0) {
        float ability    = ap + b_a[0];
        float difficulty = dp + b_d[0];
        float preq       = fabsf(prereq_w[0]) * (pp * (1.0f / (float)H));
        float gap  = ability - difficulty + preq;
        float prob = 1.0f / (1.0f + __expf(-gap));
        out[b]     = prob;
        out[B + b] = gap;
    }
}

extern "C" void kernel_launch(void* const* d_in, const int* in_sizes, int n_in,
                              void* d_out, int out_size, void* d_ws, size_t ws_size,
                              hipStream_t stream) {
    const float* x        = (const float*)d_in[0];
    const int*   ei       = (const int*)d_in[1];
    const int*   target   = (const int*)d_in[2];
    const float* pmask    = (const float*)d_in[3];
    const float* ne       = (const float*)d_in[4];
    const float* W_sp     = (const float*)d_in[5];
    const float* b_sp     = (const float*)d_in[6];
    const float* W_g      = (const float*)d_in[7];
    const float* b_g      = (const float*)d_in[8];
    const float* W_d      = (const float*)d_in[9];
    const float* b_d      = (const float*)d_in[10];
    const float* W_a      = (const float*)d_in[11];
    const float* b_a      = (const float*)d_in[12];
    const float* prereq_w = (const float*)d_in[13];

    const int nE = in_sizes[1] / 2;

    char* ws = (char*)d_ws;
    unsigned*        cnt  = (unsigned*)(ws + OFF_CNT);
    float*           wr_  = (float*)(ws + OFF_WR);
    float*           pr_  = (float*)(ws + OFF_PR);
    float*           nlr  = (float*)(ws + OFF_NLR);
    unsigned short*  cols = (unsigned short*)(ws + OFF_COLS);
    float*           tgt  = (float*)(ws + OFF_TGT);
    float*           uvec = (float*)(ws + OFF_UV);
    unsigned*        rec  = (unsigned*)(ws + OFF_REC);

    // ws poisoned 0xAA once, never re-poisoned between replays -> zero every call
    k_zero<<<(unsigned)(ZERO_END / 16 + 255) / 256, 256, 0, stream>>>((float4*)ws);
    k_edges<<<(nE + 255) / 256, 256, 0, stream>>>(ei, nE, cnt, cols);
    k_prep<<<N / 8, 256, 0, stream>>>(ne, W_g, W_sp, b_sp, x, pmask, cnt, cols,
                                      rec, uvec);
    k_spmm<<<N / 32, 1024, 0, stream>>>(rec, cnt, cols, uvec, b_g, target,
                                        wr_, pr_, nlr, tgt);
    k_final<<<1, 512, 0, stream>>>(wr_, pr_, nlr, tgt, W_d, b_d, W_a, b_a,
                                   prereq_w, (float*)d_out);
}